// Round 1
// baseline (3533.442 us; speedup 1.0000x reference)
//
#include <hip/hip_runtime.h>
#include <math.h>

// ---------------------------------------------------------------------------
// CrossAttention baseline (fp32, vector-ALU SGEMM). Round 0: correctness +
// counters. Pipeline:
//   Q = query @ Wq + bq           (16384x1024x1024 NN)
//   K = kv    @ Wk + bk
//   V = kv    @ Wv + bv
//   S = Q @ K^T * 1/32            (per-batch 2048x2048x1024 NT) -> d_out attn
//   attn = softmax(mask ? S : -inf)  in-place
//   Att = attn @ V                (per-batch 2048x1024x2048 NN) -> ws (reuse Q)
//   out = Att @ Wo + bo           (16384x1024x1024 NN) -> d_out
// ---------------------------------------------------------------------------

#define TILE 128
#define KT 16

// BT=false: B is (K,N) row-major (NN).  BT=true: B is (N,K) row-major (NT).
// All of M,N multiples of 128 and K multiple of 16 in this problem: no bounds
// checks needed.
template <bool BT>
__global__ __launch_bounds__(256) void sgemm_kernel(
    const float* __restrict__ A, const float* __restrict__ B,
    float* __restrict__ C, const float* __restrict__ bias, float alpha,
    int M, int N, int K, long long sA, long long sB, long long sC) {
  __shared__ float As[KT][TILE];
  __shared__ float Bs[KT][TILE];

  const int t = threadIdx.x;
  const int tx = t & 15;   // 16 thread-cols * 8 = 128 N
  const int ty = t >> 4;   // 16 thread-rows * 8 = 128 M
  const int m0 = blockIdx.y * TILE;
  const int n0 = blockIdx.x * TILE;

  const float* Ab = A + (long long)blockIdx.z * sA;
  const float* Bb = B + (long long)blockIdx.z * sB;
  float* Cb = C + (long long)blockIdx.z * sC;

  float acc[8][8];
#pragma unroll
  for (int i = 0; i < 8; ++i)
#pragma unroll
    for (int j = 0; j < 8; ++j) acc[i][j] = 0.0f;

  for (int k0 = 0; k0 < K; k0 += KT) {
    // ---- stage A tile (128 rows x 16 k), stored transposed As[k][m] ----
#pragma unroll
    for (int i = 0; i < 2; ++i) {
      const int idx = t + i * 256;       // 0..511 float4 slots
      const int row = idx >> 2;          // 0..127
      const int k4 = (idx & 3) << 2;     // 0,4,8,12
      const float4 v = *reinterpret_cast<const float4*>(
          Ab + (long long)(m0 + row) * K + (k0 + k4));
      As[k4 + 0][row] = v.x;
      As[k4 + 1][row] = v.y;
      As[k4 + 2][row] = v.z;
      As[k4 + 3][row] = v.w;
    }
    // ---- stage B tile, stored Bs[k][n] ----
    if constexpr (BT) {
#pragma unroll
      for (int i = 0; i < 2; ++i) {
        const int idx = t + i * 256;
        const int col = idx >> 2;        // n index 0..127
        const int k4 = (idx & 3) << 2;
        const float4 v = *reinterpret_cast<const float4*>(
            Bb + (long long)(n0 + col) * K + (k0 + k4));
        Bs[k4 + 0][col] = v.x;
        Bs[k4 + 1][col] = v.y;
        Bs[k4 + 2][col] = v.z;
        Bs[k4 + 3][col] = v.w;
      }
    } else {
#pragma unroll
      for (int i = 0; i < 2; ++i) {
        const int idx = t + i * 256;
        const int kk = idx >> 5;         // 0..15
        const int n4 = (idx & 31) << 2;  // 0..124
        *reinterpret_cast<float4*>(&Bs[kk][n4]) =
            *reinterpret_cast<const float4*>(
                Bb + (long long)(k0 + kk) * N + (n0 + n4));
      }
    }
    __syncthreads();

    // ---- 8x8 outer-product accumulate ----
#pragma unroll
    for (int kk = 0; kk < KT; ++kk) {
      float a[8], bv[8];
      *reinterpret_cast<float4*>(&a[0]) =
          *reinterpret_cast<const float4*>(&As[kk][ty * 8]);
      *reinterpret_cast<float4*>(&a[4]) =
          *reinterpret_cast<const float4*>(&As[kk][ty * 8 + 4]);
      *reinterpret_cast<float4*>(&bv[0]) =
          *reinterpret_cast<const float4*>(&Bs[kk][tx * 8]);
      *reinterpret_cast<float4*>(&bv[4]) =
          *reinterpret_cast<const float4*>(&Bs[kk][tx * 8 + 4]);
#pragma unroll
      for (int i = 0; i < 8; ++i)
#pragma unroll
        for (int j = 0; j < 8; ++j)
          acc[i][j] = fmaf(a[i], bv[j], acc[i][j]);
    }
    __syncthreads();
  }

  // ---- epilogue: alpha, optional bias, float4 stores ----
#pragma unroll
  for (int i = 0; i < 8; ++i) {
    const long long row = m0 + ty * 8 + i;
#pragma unroll
    for (int j = 0; j < 8; j += 4) {
      const int col = n0 + tx * 8 + j;
      float4 r;
      r.x = acc[i][j + 0] * alpha;
      r.y = acc[i][j + 1] * alpha;
      r.z = acc[i][j + 2] * alpha;
      r.w = acc[i][j + 3] * alpha;
      if (bias) {
        r.x += bias[col + 0];
        r.y += bias[col + 1];
        r.z += bias[col + 2];
        r.w += bias[col + 3];
      }
      *reinterpret_cast<float4*>(Cb + row * N + col) = r;
    }
  }
}

// ---------------------------------------------------------------------------
// Row softmax over KL=2048, with int mask (0 -> -inf), in place.
// One 256-thread block per row; 8 elements/thread.
// ---------------------------------------------------------------------------
__device__ __forceinline__ float wave_max64(float v) {
#pragma unroll
  for (int o = 32; o > 0; o >>= 1) v = fmaxf(v, __shfl_xor(v, o, 64));
  return v;
}
__device__ __forceinline__ float wave_sum64(float v) {
#pragma unroll
  for (int o = 32; o > 0; o >>= 1) v += __shfl_xor(v, o, 64);
  return v;
}

__global__ __launch_bounds__(256) void softmax_kernel(
    float* __restrict__ S, const int* __restrict__ mask) {
  const long long base = (long long)blockIdx.x * 2048;
  float* row = S + base;
  const int* mrow = mask + base;
  const int t = threadIdx.x;

  float vals[8];
  float lmax = -INFINITY;
#pragma unroll
  for (int i = 0; i < 2; ++i) {
    const int idx = (t + i * 256) * 4;
    const float4 v = *reinterpret_cast<const float4*>(row + idx);
    const int4 m = *reinterpret_cast<const int4*>(mrow + idx);
    vals[i * 4 + 0] = m.x ? v.x : -INFINITY;
    vals[i * 4 + 1] = m.y ? v.y : -INFINITY;
    vals[i * 4 + 2] = m.z ? v.z : -INFINITY;
    vals[i * 4 + 3] = m.w ? v.w : -INFINITY;
  }
#pragma unroll
  for (int i = 0; i < 8; ++i) lmax = fmaxf(lmax, vals[i]);

  __shared__ float red[4];
  const float wm = wave_max64(lmax);
  if ((t & 63) == 0) red[t >> 6] = wm;
  __syncthreads();
  const float rmax = fmaxf(fmaxf(red[0], red[1]), fmaxf(red[2], red[3]));
  __syncthreads();

  float lsum = 0.0f;
#pragma unroll
  for (int i = 0; i < 8; ++i) {
    const float e = __expf(vals[i] - rmax);
    vals[i] = e;
    lsum += e;
  }
  const float wsum = wave_sum64(lsum);
  if ((t & 63) == 0) red[t >> 6] = wsum;
  __syncthreads();
  const float inv = 1.0f / (red[0] + red[1] + red[2] + red[3]);

#pragma unroll
  for (int i = 0; i < 2; ++i) {
    const int idx = (t + i * 256) * 4;
    float4 o;
    o.x = vals[i * 4 + 0] * inv;
    o.y = vals[i * 4 + 1] * inv;
    o.z = vals[i * 4 + 2] * inv;
    o.w = vals[i * 4 + 3] * inv;
    *reinterpret_cast<float4*>(row + idx) = o;
  }
}

// ---------------------------------------------------------------------------
extern "C" void kernel_launch(void* const* d_in, const int* in_sizes, int n_in,
                              void* d_out, int out_size, void* d_ws,
                              size_t ws_size, hipStream_t stream) {
  const float* query = (const float*)d_in[0];
  const float* keyv = (const float*)d_in[1];
  const int* mask = (const int*)d_in[2];
  const float* Wq = (const float*)d_in[3];
  const float* bq = (const float*)d_in[4];
  const float* Wk = (const float*)d_in[5];
  const float* bk = (const float*)d_in[6];
  const float* Wv = (const float*)d_in[7];
  const float* bv = (const float*)d_in[8];
  const float* Wo = (const float*)d_in[9];
  const float* bo = (const float*)d_in[10];

  const int B = 8, QL = 2048, KL = 2048, D = 1024;
  const long long ML = (long long)B * QL;  // 16384 total query rows

  float* out = (float*)d_out;                 // (B,QL,D)
  float* attn = out + ML * D;                 // (B,QL,KL) — output 1
  float* Qb = (float*)d_ws;                   // 64 MB
  float* Kb = Qb + ML * D;                    // 64 MB
  float* Vb = Kb + ML * D;                    // 64 MB  (ws total: 192 MB)
  float* Att = Qb;  // Q is dead after scores GEMM; reuse its slot

  const dim3 blk(256);

  // Projections: (16384 x 1024) = X @ W + b
  sgemm_kernel<false><<<dim3(D / 128, ML / 128, 1), blk, 0, stream>>>(
      query, Wq, Qb, bq, 1.0f, (int)ML, D, D, 0, 0, 0);
  sgemm_kernel<false><<<dim3(D / 128, ML / 128, 1), blk, 0, stream>>>(
      keyv, Wk, Kb, bk, 1.0f, (int)ML, D, D, 0, 0, 0);
  sgemm_kernel<false><<<dim3(D / 128, ML / 128, 1), blk, 0, stream>>>(
      keyv, Wv, Vb, bv, 1.0f, (int)ML, D, D, 0, 0, 0);

  // Scores: per-batch Q @ K^T * 1/sqrt(1024) -> attn region of d_out
  sgemm_kernel<true><<<dim3(KL / 128, QL / 128, B), blk, 0, stream>>>(
      Qb, Kb, attn, nullptr, 0.03125f, QL, KL, D, (long long)QL * D,
      (long long)KL * D, (long long)QL * KL);

  // Softmax in place (mask applied)
  softmax_kernel<<<dim3(B * QL), blk, 0, stream>>>(attn, mask);

  // Attended: per-batch attn @ V -> Att (ws)
  sgemm_kernel<false><<<dim3(D / 128, QL / 128, B), blk, 0, stream>>>(
      attn, Vb, Att, nullptr, 1.0f, QL, D, KL, (long long)QL * KL,
      (long long)KL * D, (long long)QL * D);

  // Output projection: Att @ Wo + bo -> d_out
  sgemm_kernel<false><<<dim3(D / 128, ML / 128, 1), blk, 0, stream>>>(
      Att, Wo, out, bo, 1.0f, (int)ML, D, D, 0, 0, 0);
}

// Round 2
// 1484.130 us; speedup vs baseline: 2.3808x; 2.3808x over previous
//
#include <hip/hip_runtime.h>
#include <hip/hip_bf16.h>
#include <math.h>

// ---------------------------------------------------------------------------
// CrossAttention round 1: all GEMMs on MFMA via split-bf16 (3-product
// Markidis: hi*hi + hi*lo + lo*hi, fp32 accumulate). fp32 tensors in memory;
// conversion happens in the GEMM staging path (global->reg->cvt->LDS).
// Single NT GEMM kernel (both operands row-major, K contiguous); weights and
// V are transposed by a tiled transpose kernel so every GEMM is NT.
// ---------------------------------------------------------------------------

typedef __attribute__((ext_vector_type(8))) short short8;   // 8 bf16 = 4 VGPR
typedef __attribute__((ext_vector_type(4))) float floatx4;  // MFMA acc

__device__ __forceinline__ short f2bf(float x) {
  __hip_bfloat16 h = __float2bfloat16(x);
  return __builtin_bit_cast(short, h);
}
__device__ __forceinline__ float bf2f(short s) {
  __hip_bfloat16 h = __builtin_bit_cast(__hip_bfloat16, s);
  return __bfloat162float(h);
}

#define BM 128
#define BN 128
#define BK 32
#define LDSW 40  // LDS row stride in shorts (32 + 8 pad = 80 B, 16B-aligned)

// C(M,N) = alpha * A(M,K) . B(N,K)^T + bias  — NT, all row-major.
// M,N multiples of 128; K multiple of 32.
__global__ __launch_bounds__(256, 2) void gemm_nt_split(
    const float* __restrict__ A, const float* __restrict__ B,
    float* __restrict__ C, const float* __restrict__ bias, float alpha,
    int M, int N, int K, long long sA, long long sB, long long sC) {
  __shared__ short Ah[BM * LDSW];
  __shared__ short Al[BM * LDSW];
  __shared__ short Bh[BN * LDSW];
  __shared__ short Bl[BN * LDSW];

  const int t = threadIdx.x;
  const int lane = t & 63;
  const int wave = t >> 6;       // 0..3
  const int wy = wave >> 1;      // 2x2 wave grid, each wave 64x64
  const int wx = wave & 1;
  const int lm = lane & 15;
  const int q = lane >> 4;       // quad 0..3

  const int m0 = blockIdx.y * BM;
  const int n0 = blockIdx.x * BN;

  const float* Ab = A + (long long)blockIdx.z * sA;
  const float* Bb = B + (long long)blockIdx.z * sB;
  float* Cb = C + (long long)blockIdx.z * sC;

  // staging map: thread -> 16 consecutive fp32 (half a BK row)
  const int sr = t >> 1;             // row 0..127
  const int sk = (t & 1) << 4;      // col 0 or 16

  floatx4 acc[4][4];
#pragma unroll
  for (int i = 0; i < 4; ++i)
#pragma unroll
    for (int j = 0; j < 4; ++j) acc[i][j] = (floatx4)(0.0f);

  for (int k0 = 0; k0 < K; k0 += BK) {
    __syncthreads();  // previous iteration's frag reads must be done

    // ---- stage A half-row: load 16 fp32, split, write hi/lo bf16 ----
    {
      const float4* src = reinterpret_cast<const float4*>(
          Ab + (long long)(m0 + sr) * K + (k0 + sk));
      float x[16];
#pragma unroll
      for (int i = 0; i < 4; ++i) {
        const float4 v = src[i];
        x[i * 4 + 0] = v.x; x[i * 4 + 1] = v.y;
        x[i * 4 + 2] = v.z; x[i * 4 + 3] = v.w;
      }
      short8 h0, h1, l0, l1;
#pragma unroll
      for (int i = 0; i < 8; ++i) {
        short h = f2bf(x[i]);
        h0[i] = h;
        l0[i] = f2bf(x[i] - bf2f(h));
      }
#pragma unroll
      for (int i = 0; i < 8; ++i) {
        short h = f2bf(x[8 + i]);
        h1[i] = h;
        l1[i] = f2bf(x[8 + i] - bf2f(h));
      }
      const int o = sr * LDSW + sk;
      *reinterpret_cast<short8*>(&Ah[o]) = h0;
      *reinterpret_cast<short8*>(&Ah[o + 8]) = h1;
      *reinterpret_cast<short8*>(&Al[o]) = l0;
      *reinterpret_cast<short8*>(&Al[o + 8]) = l1;
    }
    // ---- stage B half-row (NT: B is (N,K) row-major, same pattern) ----
    {
      const float4* src = reinterpret_cast<const float4*>(
          Bb + (long long)(n0 + sr) * K + (k0 + sk));
      float x[16];
#pragma unroll
      for (int i = 0; i < 4; ++i) {
        const float4 v = src[i];
        x[i * 4 + 0] = v.x; x[i * 4 + 1] = v.y;
        x[i * 4 + 2] = v.z; x[i * 4 + 3] = v.w;
      }
      short8 h0, h1, l0, l1;
#pragma unroll
      for (int i = 0; i < 8; ++i) {
        short h = f2bf(x[i]);
        h0[i] = h;
        l0[i] = f2bf(x[i] - bf2f(h));
      }
#pragma unroll
      for (int i = 0; i < 8; ++i) {
        short h = f2bf(x[8 + i]);
        h1[i] = h;
        l1[i] = f2bf(x[8 + i] - bf2f(h));
      }
      const int o = sr * LDSW + sk;
      *reinterpret_cast<short8*>(&Bh[o]) = h0;
      *reinterpret_cast<short8*>(&Bh[o + 8]) = h1;
      *reinterpret_cast<short8*>(&Bl[o]) = l0;
      *reinterpret_cast<short8*>(&Bl[o + 8]) = l1;
    }
    __syncthreads();

    // ---- fragments: A[m = lane&15][k = q*8+j], B[k = q*8+j][n = lane&15]
    short8 fah[4], fal[4], fbh[4], fbl[4];
#pragma unroll
    for (int mt = 0; mt < 4; ++mt) {
      const int row = wy * 64 + mt * 16 + lm;
      fah[mt] = *reinterpret_cast<const short8*>(&Ah[row * LDSW + q * 8]);
      fal[mt] = *reinterpret_cast<const short8*>(&Al[row * LDSW + q * 8]);
    }
#pragma unroll
    for (int nt = 0; nt < 4; ++nt) {
      const int row = wx * 64 + nt * 16 + lm;
      fbh[nt] = *reinterpret_cast<const short8*>(&Bh[row * LDSW + q * 8]);
      fbl[nt] = *reinterpret_cast<const short8*>(&Bl[row * LDSW + q * 8]);
    }

#pragma unroll
    for (int mt = 0; mt < 4; ++mt)
#pragma unroll
      for (int nt = 0; nt < 4; ++nt) {
        acc[mt][nt] = __builtin_amdgcn_mfma_f32_16x16x32_bf16(
            fah[mt], fbh[nt], acc[mt][nt], 0, 0, 0);
        acc[mt][nt] = __builtin_amdgcn_mfma_f32_16x16x32_bf16(
            fah[mt], fbl[nt], acc[mt][nt], 0, 0, 0);
        acc[mt][nt] = __builtin_amdgcn_mfma_f32_16x16x32_bf16(
            fal[mt], fbh[nt], acc[mt][nt], 0, 0, 0);
      }
  }

  // ---- epilogue: C/D layout col = lane&15, row = q*4 + reg ----
#pragma unroll
  for (int nt = 0; nt < 4; ++nt) {
    const int col = n0 + wx * 64 + nt * 16 + lm;
    const float bv = bias ? bias[col] : 0.0f;
#pragma unroll
    for (int mt = 0; mt < 4; ++mt) {
      const int rbase = m0 + wy * 64 + mt * 16 + q * 4;
#pragma unroll
      for (int i = 0; i < 4; ++i) {
        Cb[(long long)(rbase + i) * N + col] = acc[mt][nt][i] * alpha + bv;
      }
    }
  }
}

// ---------------------------------------------------------------------------
// Tiled fp32 transpose: out(C,R) = in(R,C)^T, 32x32 tiles, batched.
// ---------------------------------------------------------------------------
__global__ __launch_bounds__(256) void transpose_kernel(
    const float* __restrict__ in, float* __restrict__ out, int R, int C,
    long long sIn, long long sOut) {
  __shared__ float tile[32][33];
  const float* ib = in + (long long)blockIdx.z * sIn;
  float* ob = out + (long long)blockIdx.z * sOut;
  const int c0 = blockIdx.x * 32, r0 = blockIdx.y * 32;
  const int tx = threadIdx.x & 31, ty = threadIdx.x >> 5;  // 32 x 8
#pragma unroll
  for (int i = 0; i < 4; ++i)
    tile[ty + i * 8][tx] = ib[(long long)(r0 + ty + i * 8) * C + c0 + tx];
  __syncthreads();
#pragma unroll
  for (int i = 0; i < 4; ++i)
    ob[(long long)(c0 + ty + i * 8) * R + r0 + tx] = tile[tx][ty + i * 8];
}

// ---------------------------------------------------------------------------
// Row softmax over KL=2048 with int mask (0 -> -inf), in place. (round 0)
// ---------------------------------------------------------------------------
__device__ __forceinline__ float wave_max64(float v) {
#pragma unroll
  for (int o = 32; o > 0; o >>= 1) v = fmaxf(v, __shfl_xor(v, o, 64));
  return v;
}
__device__ __forceinline__ float wave_sum64(float v) {
#pragma unroll
  for (int o = 32; o > 0; o >>= 1) v += __shfl_xor(v, o, 64);
  return v;
}

__global__ __launch_bounds__(256) void softmax_kernel(
    float* __restrict__ S, const int* __restrict__ mask) {
  const long long base = (long long)blockIdx.x * 2048;
  float* row = S + base;
  const int* mrow = mask + base;
  const int t = threadIdx.x;

  float vals[8];
  float lmax = -INFINITY;
#pragma unroll
  for (int i = 0; i < 2; ++i) {
    const int idx = (t + i * 256) * 4;
    const float4 v = *reinterpret_cast<const float4*>(row + idx);
    const int4 m = *reinterpret_cast<const int4*>(mrow + idx);
    vals[i * 4 + 0] = m.x ? v.x : -INFINITY;
    vals[i * 4 + 1] = m.y ? v.y : -INFINITY;
    vals[i * 4 + 2] = m.z ? v.z : -INFINITY;
    vals[i * 4 + 3] = m.w ? v.w : -INFINITY;
  }
#pragma unroll
  for (int i = 0; i < 8; ++i) lmax = fmaxf(lmax, vals[i]);

  __shared__ float red[4];
  const float wm = wave_max64(lmax);
  if ((t & 63) == 0) red[t >> 6] = wm;
  __syncthreads();
  const float rmax = fmaxf(fmaxf(red[0], red[1]), fmaxf(red[2], red[3]));
  __syncthreads();

  float lsum = 0.0f;
#pragma unroll
  for (int i = 0; i < 8; ++i) {
    const float e = __expf(vals[i] - rmax);
    vals[i] = e;
    lsum += e;
  }
  const float wsum = wave_sum64(lsum);
  if ((t & 63) == 0) red[t >> 6] = wsum;
  __syncthreads();
  const float inv = 1.0f / (red[0] + red[1] + red[2] + red[3]);

#pragma unroll
  for (int i = 0; i < 2; ++i) {
    const int idx = (t + i * 256) * 4;
    float4 o;
    o.x = vals[i * 4 + 0] * inv;
    o.y = vals[i * 4 + 1] * inv;
    o.z = vals[i * 4 + 2] * inv;
    o.w = vals[i * 4 + 3] * inv;
    *reinterpret_cast<float4*>(row + idx) = o;
  }
}

// ---------------------------------------------------------------------------
extern "C" void kernel_launch(void* const* d_in, const int* in_sizes, int n_in,
                              void* d_out, int out_size, void* d_ws,
                              size_t ws_size, hipStream_t stream) {
  const float* query = (const float*)d_in[0];
  const float* keyv = (const float*)d_in[1];
  const int* mask = (const int*)d_in[2];
  const float* Wq = (const float*)d_in[3];
  const float* bq = (const float*)d_in[4];
  const float* Wk = (const float*)d_in[5];
  const float* bk = (const float*)d_in[6];
  const float* Wv = (const float*)d_in[7];
  const float* bv = (const float*)d_in[8];
  const float* Wo = (const float*)d_in[9];
  const float* bo = (const float*)d_in[10];

  const int B = 8, QL = 2048, KL = 2048, D = 1024;
  const long long ML = (long long)B * QL;  // 16384

  float* out = (float*)d_out;            // (B,QL,D)
  float* attn = out + ML * D;            // (B,QL,KL) — output 1

  // ws: [Q 64MB | K 64MB | V 64MB | WqT 4MB | WkT | WvT | WoT] = 208 MB
  float* Qb = (float*)d_ws;
  float* Kb = Qb + ML * D;
  float* Vb = Kb + ML * D;
  float* WqT = Vb + ML * D;
  float* WkT = WqT + (long long)D * D;
  float* WvT = WkT + (long long)D * D;
  float* WoT = WvT + (long long)D * D;
  float* VT = Qb;   // Q dead after scores GEMM
  float* Att = Kb;  // K dead after scores GEMM

  const dim3 blk(256);

  // Weight transposes (W is (K,N); need (N,K) for NT GEMM)
  transpose_kernel<<<dim3(32, 32, 1), blk, 0, stream>>>(Wq, WqT, D, D, 0, 0);
  transpose_kernel<<<dim3(32, 32, 1), blk, 0, stream>>>(Wk, WkT, D, D, 0, 0);
  transpose_kernel<<<dim3(32, 32, 1), blk, 0, stream>>>(Wv, WvT, D, D, 0, 0);
  transpose_kernel<<<dim3(32, 32, 1), blk, 0, stream>>>(Wo, WoT, D, D, 0, 0);

  // Projections: (16384 x 1024 x 1024)
  gemm_nt_split<<<dim3(D / BN, ML / BM, 1), blk, 0, stream>>>(
      query, WqT, Qb, bq, 1.0f, (int)ML, D, D, 0, 0, 0);
  gemm_nt_split<<<dim3(D / BN, ML / BM, 1), blk, 0, stream>>>(
      keyv, WkT, Kb, bk, 1.0f, (int)ML, D, D, 0, 0, 0);
  gemm_nt_split<<<dim3(D / BN, ML / BM, 1), blk, 0, stream>>>(
      keyv, WvT, Vb, bv, 1.0f, (int)ML, D, D, 0, 0, 0);

  // Scores: per-batch Q . K^T / 32 -> attn region of d_out (NT natural)
  gemm_nt_split<<<dim3(KL / BN, QL / BM, B), blk, 0, stream>>>(
      Qb, Kb, attn, nullptr, 0.03125f, QL, KL, D, (long long)QL * D,
      (long long)KL * D, (long long)QL * KL);

  // Softmax in place
  softmax_kernel<<<dim3(B * QL), blk, 0, stream>>>(attn, mask);

  // V^T per batch: (2048,1024) -> (1024,2048), into old Q slot
  transpose_kernel<<<dim3(D / 32, KL / 32, B), blk, 0, stream>>>(
      Vb, VT, KL, D, (long long)KL * D, (long long)KL * D);

  // Attended: per-batch attn(2048x2048) . V -> NT with V^T ; -> Att (old K)
  gemm_nt_split<<<dim3(D / BN, QL / BM, B), blk, 0, stream>>>(
      attn, VT, Att, nullptr, 1.0f, QL, D, KL, (long long)QL * KL,
      (long long)D * KL, (long long)QL * D);

  // Output projection: Att . Wo^T + bo -> d_out
  gemm_nt_split<<<dim3(D / BN, ML / BM, 1), blk, 0, stream>>>(
      Att, WoT, out, bo, 1.0f, (int)ML, D, D, 0, 0, 0);
}

// Round 3
// 1033.159 us; speedup vs baseline: 3.4200x; 1.4365x over previous
//
#include <hip/hip_runtime.h>
#include <hip/hip_bf16.h>
#include <math.h>

// ---------------------------------------------------------------------------
// Round 2: precision-tiered MFMA pipeline.
//   Q/K/V projections, scores, attn*V : single-product bf16 (error analysis:
//     softmax damping / P-averaging keeps their contribution < 1e-4 abs)
//   out-projection                    : 3-product split-bf16 (only GEMM whose
//     bf16 error (~1.6e-3) would breach the 1.2e-3 threshold)
// All GEMM staging via global_load_lds (16B) for pre-split operands; fp32
// operands (query/kv) convert to bf16-hi in-register (1 cvt/elem).
// ---------------------------------------------------------------------------

typedef __attribute__((ext_vector_type(8))) short short8;   // 8 bf16
typedef __attribute__((ext_vector_type(4))) float floatx4;  // MFMA acc

__device__ __forceinline__ unsigned short f2bf(float x) {
  return __builtin_bit_cast(unsigned short, __float2bfloat16(x));
}
__device__ __forceinline__ float bf2f(unsigned short s) {
  unsigned int u = ((unsigned int)s) << 16;
  return __builtin_bit_cast(float, u);
}

typedef const unsigned int __attribute__((address_space(1))) ga_u32;
typedef unsigned int __attribute__((address_space(3))) lds_u32;
__device__ __forceinline__ void gl_lds16(const void* g, void* l) {
  __builtin_amdgcn_global_load_lds((ga_u32*)g, (lds_u32*)l, 16, 0, 0);
}

#define BM 128
#define BN 128
#define BK 32

// AMODE: 0 = A fp32 (convert hi in staging), 1 = A bf16-hi, 2 = A split h+l
// BSPL : B split (h+l) vs hi-only
// EPI  : 0 = fp32 (+bias), 1 = bf16 (alpha, opt bias), 3 = bf16 transposed
//        per-batch (+bias), 4 = split h+l
template <int AMODE, bool BSPL, int EPI>
__global__ __launch_bounds__(256) void gemm_nt(
    const void* __restrict__ Apv, const unsigned short* __restrict__ Alp,
    const unsigned short* __restrict__ Bhp,
    const unsigned short* __restrict__ Blp, void* __restrict__ Cp,
    unsigned short* __restrict__ Cl, const float* __restrict__ bias,
    float alpha, int M, int N, int K, int Mt, long long sA, long long sB,
    long long sC) {
  __shared__ unsigned short As_h[BM * BK];
  __shared__ unsigned short Bs_h[BN * BK];
  __shared__ unsigned short As_l[(AMODE == 2) ? BM * BK : 8];
  __shared__ unsigned short Bs_l[BSPL ? BN * BK : 8];

  const int t = threadIdx.x;
  const int lane = t & 63;
  const int wave = t >> 6;
  const int wy = wave >> 1, wx = wave & 1;
  const int lm = lane & 15, q = lane >> 4;
  const int m0 = blockIdx.y * BM, n0 = blockIdx.x * BN;
  const long long zb = blockIdx.z;

  const float* Af = nullptr;
  const unsigned short* Ahg = nullptr;
  const unsigned short* Alg = nullptr;
  if constexpr (AMODE == 0) {
    Af = (const float*)Apv + zb * sA;
  } else {
    Ahg = (const unsigned short*)Apv + zb * sA;
    if constexpr (AMODE == 2) Alg = Alp + zb * sA;
  }
  const unsigned short* Bhg = Bhp + zb * sB;
  const unsigned short* Blg = BSPL ? (Blp + zb * sB) : nullptr;

  floatx4 acc[4][4];
#pragma unroll
  for (int i = 0; i < 4; ++i)
#pragma unroll
    for (int j = 0; j < 4; ++j) acc[i][j] = (floatx4)(0.0f);

  const int ch_row = lane >> 2;        // row within a 16-row async chunk
  const int ch_off = (lane & 3) << 3;  // k-offset in shorts (16B units)

  for (int k0 = 0; k0 < K; k0 += BK) {
    float4 av[4];
    if constexpr (AMODE == 0) {
      const float* ap =
          Af + (long long)(m0 + (t >> 1)) * K + (k0 + ((t & 1) << 4));
#pragma unroll
      for (int i = 0; i < 4; ++i)
        av[i] = reinterpret_cast<const float4*>(ap)[i];
    }
    __syncthreads();  // prev iteration's fragment reads complete

    if constexpr (AMODE == 0) {
      float x[16];
#pragma unroll
      for (int i = 0; i < 4; ++i) {
        x[i * 4 + 0] = av[i].x; x[i * 4 + 1] = av[i].y;
        x[i * 4 + 2] = av[i].z; x[i * 4 + 3] = av[i].w;
      }
      short8 h0, h1;
#pragma unroll
      for (int i = 0; i < 8; ++i) h0[i] = (short)f2bf(x[i]);
#pragma unroll
      for (int i = 0; i < 8; ++i) h1[i] = (short)f2bf(x[8 + i]);
      const int o = (t >> 1) * BK + ((t & 1) << 4);
      *reinterpret_cast<short8*>(&As_h[o]) = h0;
      *reinterpret_cast<short8*>(&As_h[o + 8]) = h1;
    } else {
#pragma unroll
      for (int j = 0; j < 2; ++j) {
        const int chunk = wave * 2 + j;
        const int row = chunk * 16 + ch_row;
        gl_lds16(Ahg + (long long)(m0 + row) * K + k0 + ch_off,
                 &As_h[chunk * 512 + lane * 8]);
        if constexpr (AMODE == 2)
          gl_lds16(Alg + (long long)(m0 + row) * K + k0 + ch_off,
                   &As_l[chunk * 512 + lane * 8]);
      }
    }
#pragma unroll
    for (int j = 0; j < 2; ++j) {
      const int chunk = wave * 2 + j;
      const int row = chunk * 16 + ch_row;
      gl_lds16(Bhg + (long long)(n0 + row) * K + k0 + ch_off,
               &Bs_h[chunk * 512 + lane * 8]);
      if constexpr (BSPL)
        gl_lds16(Blg + (long long)(n0 + row) * K + k0 + ch_off,
                 &Bs_l[chunk * 512 + lane * 8]);
    }
    __syncthreads();  // drains vmcnt (async LDS writes) + lgkm

    short8 fa[4], fb[4], fal[4], fbl[4];
#pragma unroll
    for (int mt = 0; mt < 4; ++mt) {
      const int row = wy * 64 + mt * 16 + lm;
      fa[mt] = *reinterpret_cast<const short8*>(&As_h[row * BK + q * 8]);
      if constexpr (AMODE == 2)
        fal[mt] = *reinterpret_cast<const short8*>(&As_l[row * BK + q * 8]);
    }
#pragma unroll
    for (int nt = 0; nt < 4; ++nt) {
      const int row = wx * 64 + nt * 16 + lm;
      fb[nt] = *reinterpret_cast<const short8*>(&Bs_h[row * BK + q * 8]);
      if constexpr (BSPL)
        fbl[nt] = *reinterpret_cast<const short8*>(&Bs_l[row * BK + q * 8]);
    }

#pragma unroll
    for (int mt = 0; mt < 4; ++mt)
#pragma unroll
      for (int nt = 0; nt < 4; ++nt) {
        acc[mt][nt] = __builtin_amdgcn_mfma_f32_16x16x32_bf16(
            fa[mt], fb[nt], acc[mt][nt], 0, 0, 0);
        if constexpr (AMODE == 2 && BSPL) {
          acc[mt][nt] = __builtin_amdgcn_mfma_f32_16x16x32_bf16(
              fa[mt], fbl[nt], acc[mt][nt], 0, 0, 0);
          acc[mt][nt] = __builtin_amdgcn_mfma_f32_16x16x32_bf16(
              fal[mt], fb[nt], acc[mt][nt], 0, 0, 0);
        }
      }
  }

  // ---- epilogue; C/D layout: col = lane&15, row = q*4 + reg ----
#pragma unroll
  for (int nt = 0; nt < 4; ++nt) {
    const int col = n0 + wx * 64 + nt * 16 + lm;
    const float bv = bias ? bias[col] : 0.0f;
#pragma unroll
    for (int mt = 0; mt < 4; ++mt) {
      const int rbase = m0 + wy * 64 + mt * 16 + q * 4;
      if constexpr (EPI == 3) {
        const int b = rbase / Mt;
        const int kk = rbase - b * Mt;
        unsigned short* dst =
            (unsigned short*)Cp + (long long)b * sC + (long long)col * Mt + kk;
        ushort4 pk;
        pk.x = f2bf(acc[mt][nt][0] * alpha + bv);
        pk.y = f2bf(acc[mt][nt][1] * alpha + bv);
        pk.z = f2bf(acc[mt][nt][2] * alpha + bv);
        pk.w = f2bf(acc[mt][nt][3] * alpha + bv);
        *reinterpret_cast<ushort4*>(dst) = pk;
      } else {
#pragma unroll
        for (int i = 0; i < 4; ++i) {
          const long long idx = zb * sC + (long long)(rbase + i) * N + col;
          const float x = acc[mt][nt][i] * alpha + bv;
          if constexpr (EPI == 0) {
            ((float*)Cp)[idx] = x;
          } else if constexpr (EPI == 1) {
            ((unsigned short*)Cp)[idx] = f2bf(x);
          } else {  // EPI == 4
            const unsigned short h = f2bf(x);
            ((unsigned short*)Cp)[idx] = h;
            Cl[idx] = f2bf(x - bf2f(h));
          }
        }
      }
    }
  }
}

// ---------------------------------------------------------------------------
// Weight prep: T = W^T as bf16-hi (and optional lo). W is (R,C) fp32.
// ---------------------------------------------------------------------------
__global__ __launch_bounds__(256) void prep_w(const float* __restrict__ W,
                                              unsigned short* __restrict__ Th,
                                              unsigned short* __restrict__ Tl,
                                              int R, int C) {
  __shared__ float tile[32][33];
  const int c0 = blockIdx.x * 32, r0 = blockIdx.y * 32;
  const int tx = threadIdx.x & 31, ty = threadIdx.x >> 5;
#pragma unroll
  for (int i = 0; i < 4; ++i)
    tile[ty + i * 8][tx] = W[(long long)(r0 + ty + i * 8) * C + c0 + tx];
  __syncthreads();
#pragma unroll
  for (int i = 0; i < 4; ++i) {
    const float x = tile[tx][ty + i * 8];
    const long long idx = (long long)(c0 + ty + i * 8) * R + r0 + tx;
    const unsigned short h = f2bf(x);
    Th[idx] = h;
    if (Tl) Tl[idx] = f2bf(x - bf2f(h));
  }
}

// ---------------------------------------------------------------------------
// Softmax: reads bf16 scores, int mask; writes fp32 attn (d_out) + bf16 Ph.
// ---------------------------------------------------------------------------
__device__ __forceinline__ float wave_max64(float v) {
#pragma unroll
  for (int o = 32; o > 0; o >>= 1) v = fmaxf(v, __shfl_xor(v, o, 64));
  return v;
}
__device__ __forceinline__ float wave_sum64(float v) {
#pragma unroll
  for (int o = 32; o > 0; o >>= 1) v += __shfl_xor(v, o, 64);
  return v;
}

__global__ __launch_bounds__(256) void softmax_kernel(
    const unsigned short* __restrict__ Sh, const int* __restrict__ mask,
    float* __restrict__ attn, unsigned short* __restrict__ Ph) {
  const long long base = (long long)blockIdx.x * 2048;
  const int t = threadIdx.x;

  float vals[8];
  float lmax = -INFINITY;
#pragma unroll
  for (int g = 0; g < 2; ++g) {
    const int idx = (t + g * 256) * 4;
    const uint2 u = *reinterpret_cast<const uint2*>(Sh + base + idx);
    const int4 m = *reinterpret_cast<const int4*>(mask + base + idx);
    vals[g * 4 + 0] = m.x ? bf2f((unsigned short)(u.x & 0xffff)) : -INFINITY;
    vals[g * 4 + 1] = m.y ? bf2f((unsigned short)(u.x >> 16)) : -INFINITY;
    vals[g * 4 + 2] = m.z ? bf2f((unsigned short)(u.y & 0xffff)) : -INFINITY;
    vals[g * 4 + 3] = m.w ? bf2f((unsigned short)(u.y >> 16)) : -INFINITY;
  }
#pragma unroll
  for (int i = 0; i < 8; ++i) lmax = fmaxf(lmax, vals[i]);

  __shared__ float red[4];
  const float wm = wave_max64(lmax);
  if ((t & 63) == 0) red[t >> 6] = wm;
  __syncthreads();
  const float rmax = fmaxf(fmaxf(red[0], red[1]), fmaxf(red[2], red[3]));
  __syncthreads();

  float lsum = 0.0f;
#pragma unroll
  for (int i = 0; i < 8; ++i) {
    const float e = __expf(vals[i] - rmax);
    vals[i] = e;
    lsum += e;
  }
  const float wsum = wave_sum64(lsum);
  if ((t & 63) == 0) red[t >> 6] = wsum;
  __syncthreads();
  const float inv = 1.0f / (red[0] + red[1] + red[2] + red[3]);

#pragma unroll
  for (int g = 0; g < 2; ++g) {
    const int idx = (t + g * 256) * 4;
    float4 o;
    o.x = vals[g * 4 + 0] * inv;
    o.y = vals[g * 4 + 1] * inv;
    o.z = vals[g * 4 + 2] * inv;
    o.w = vals[g * 4 + 3] * inv;
    *reinterpret_cast<float4*>(attn + base + idx) = o;
    uint2 p;
    p.x = (unsigned)f2bf(o.x) | ((unsigned)f2bf(o.y) << 16);
    p.y = (unsigned)f2bf(o.z) | ((unsigned)f2bf(o.w) << 16);
    *reinterpret_cast<uint2*>(Ph + base + idx) = p;
  }
}

// ---------------------------------------------------------------------------
extern "C" void kernel_launch(void* const* d_in, const int* in_sizes, int n_in,
                              void* d_out, int out_size, void* d_ws,
                              size_t ws_size, hipStream_t stream) {
  const float* query = (const float*)d_in[0];
  const float* keyv = (const float*)d_in[1];
  const int* mask = (const int*)d_in[2];
  const float* Wq = (const float*)d_in[3];
  const float* bq = (const float*)d_in[4];
  const float* Wk = (const float*)d_in[5];
  const float* bk = (const float*)d_in[6];
  const float* Wv = (const float*)d_in[7];
  const float* bv = (const float*)d_in[8];
  const float* Wo = (const float*)d_in[9];
  const float* bo = (const float*)d_in[10];

  const int B = 8, QL = 2048, KL = 2048, D = 1024;
  const long long ML = (long long)B * QL;  // 16384

  float* out = (float*)d_out;      // (B,QL,D) fp32
  float* attn = out + ML * D;      // (B,QL,KL) fp32 — output 1

  // ws layout (170 MB total):
  //   [0,32)   Qh        — overlaid by Ph[0,64) after scores
  //   [32,64)  Kh
  //   [64,96)  VTh (B,D,KL)
  //   [96,160) Sh (bf16 scores) — overlaid by Atth[96,128)+Attl[128,160)
  //   [160,170) WqT|WkT|WvT|WoTh|WoTl (2 MB each)
  char* w = (char*)d_ws;
  unsigned short* Qh = (unsigned short*)(w);
  unsigned short* Kh = (unsigned short*)(w + (32ll << 20));
  unsigned short* VTh = (unsigned short*)(w + (64ll << 20));
  unsigned short* Sh = (unsigned short*)(w + (96ll << 20));
  unsigned short* Ph = (unsigned short*)(w);
  unsigned short* Atth = (unsigned short*)(w + (96ll << 20));
  unsigned short* Attl = (unsigned short*)(w + (128ll << 20));
  unsigned short* WqT = (unsigned short*)(w + (160ll << 20));
  unsigned short* WkT = WqT + (1ll << 20);
  unsigned short* WvT = WkT + (1ll << 20);
  unsigned short* WoTh = WvT + (1ll << 20);
  unsigned short* WoTl = WoTh + (1ll << 20);

  const dim3 blk(256);

  prep_w<<<dim3(32, 32), blk, 0, stream>>>(Wq, WqT, nullptr, D, D);
  prep_w<<<dim3(32, 32), blk, 0, stream>>>(Wk, WkT, nullptr, D, D);
  prep_w<<<dim3(32, 32), blk, 0, stream>>>(Wv, WvT, nullptr, D, D);
  prep_w<<<dim3(32, 32), blk, 0, stream>>>(Wo, WoTh, WoTl, D, D);

  // Q/K projections -> bf16-hi, row-major
  gemm_nt<0, false, 1><<<dim3(D / BN, ML / BM, 1), blk, 0, stream>>>(
      query, nullptr, WqT, nullptr, Qh, nullptr, bq, 1.0f, (int)ML, D, D, 1,
      0, 0, 0);
  gemm_nt<0, false, 1><<<dim3(D / BN, ML / BM, 1), blk, 0, stream>>>(
      keyv, nullptr, WkT, nullptr, Kh, nullptr, bk, 1.0f, (int)ML, D, D, 1,
      0, 0, 0);
  // V projection -> bf16-hi, transposed per batch: VT (B, D, KL)
  gemm_nt<0, false, 3><<<dim3(D / BN, ML / BM, 1), blk, 0, stream>>>(
      keyv, nullptr, WvT, nullptr, VTh, nullptr, bv, 1.0f, (int)ML, D, D, KL,
      0, 0, (long long)D * KL);

  // Scores: per-batch Qh . Kh^T / 32 -> Sh (bf16)
  gemm_nt<1, false, 1><<<dim3(KL / BN, QL / BM, B), blk, 0, stream>>>(
      Qh, nullptr, Kh, nullptr, Sh, nullptr, nullptr, 0.03125f, QL, KL, D, 1,
      (long long)QL * D, (long long)KL * D, (long long)QL * KL);

  // Softmax: Sh -> attn (fp32, d_out) + Ph (bf16)
  softmax_kernel<<<dim3((int)ML), blk, 0, stream>>>(Sh, mask, attn, Ph);

  // Attended: per-batch Ph . VT^T -> Att split (h+l)
  gemm_nt<1, false, 4><<<dim3(D / BN, QL / BM, B), blk, 0, stream>>>(
      Ph, nullptr, VTh, nullptr, Atth, Attl, nullptr, 1.0f, QL, D, KL, 1,
      (long long)QL * KL, (long long)D * KL, (long long)QL * D);

  // Output projection: Att(split) . WoT(split), 3-product -> d_out fp32
  gemm_nt<2, true, 0><<<dim3(D / BN, ML / BM, 1), blk, 0, stream>>>(
      Atth, Attl, WoTh, WoTl, out, nullptr, bo, 1.0f, (int)ML, D, D, 1, 0, 0,
      0);
}